// Round 9
// baseline (144.370 us; speedup 1.0000x reference)
//
#include <hip/hip_runtime.h>
#include <stdint.h>

#define MARGIN 0.2f
#define INF_BITS 0x7F800000u

typedef __attribute__((ext_vector_type(8))) short bfrag;     // 8 bf16 (4 VGPRs)
typedef __attribute__((ext_vector_type(4))) float f32x4;

__device__ __forceinline__ unsigned short f32_to_bf16(float f) {
  unsigned u = __float_as_uint(f);
  u += 0x7FFFu + ((u >> 16) & 1u);   // RNE
  return (unsigned short)(u >> 16);
}

// ---------------- Phase 0: norms, d_ap, bf16 conversion, min-init ----------------
// one wave per row (4 rows/block)
__global__ __launch_bounds__(256) void prep_kernel(
    const float* __restrict__ anchor, const float* __restrict__ positive,
    const float* __restrict__ negative,
    unsigned short* __restrict__ a_bf, unsigned short* __restrict__ n_bf,
    float* __restrict__ a2, float* __restrict__ n2, float* __restrict__ dap,
    unsigned* __restrict__ gsh, unsigned* __restrict__ gv, int D) {
  const int wid  = threadIdx.x >> 6;
  const int lane = threadIdx.x & 63;
  const int row  = blockIdx.x * 4 + wid;
  const size_t base = (size_t)row * D;
  const int epl = D >> 6;            // elements per lane (8 for D=512)
  const int k0  = lane * epl;
  float sa2 = 0.f, sdap = 0.f, sn2 = 0.f;

  for (int c = 0; c < epl; c += 8) {
    const float4* ap = (const float4*)(anchor   + base + k0 + c);
    const float4* pp = (const float4*)(positive + base + k0 + c);
    const float4* np = (const float4*)(negative + base + k0 + c);
    float4 a0 = ap[0], a1 = ap[1];
    float4 p0 = pp[0], p1 = pp[1];
    float4 v0 = np[0], v1 = np[1];
    float aa[8] = {a0.x,a0.y,a0.z,a0.w,a1.x,a1.y,a1.z,a1.w};
    float pv[8] = {p0.x,p0.y,p0.z,p0.w,p1.x,p1.y,p1.z,p1.w};
    float nn[8] = {v0.x,v0.y,v0.z,v0.w,v1.x,v1.y,v1.z,v1.w};
    #pragma unroll
    for (int e = 0; e < 8; e++) {
      sa2 += aa[e] * aa[e];
      float dd = aa[e] - pv[e];
      sdap += dd * dd;
      sn2 += nn[e] * nn[e];
    }
    unsigned au[4], nu[4];
    #pragma unroll
    for (int e = 0; e < 4; e++) {
      au[e] = (unsigned)f32_to_bf16(aa[2*e]) | ((unsigned)f32_to_bf16(aa[2*e+1]) << 16);
      nu[e] = (unsigned)f32_to_bf16(nn[2*e]) | ((unsigned)f32_to_bf16(nn[2*e+1]) << 16);
    }
    *(uint4*)(a_bf + base + k0 + c) = make_uint4(au[0], au[1], au[2], au[3]);
    *(uint4*)(n_bf + base + k0 + c) = make_uint4(nu[0], nu[1], nu[2], nu[3]);
  }
  #pragma unroll
  for (int off = 32; off > 0; off >>= 1) {
    sa2  += __shfl_down(sa2,  off);
    sdap += __shfl_down(sdap, off);
    sn2  += __shfl_down(sn2,  off);
  }
  if (lane == 0) {
    a2[row]  = sa2;
    dap[row] = sdap;
    n2[row]  = sn2;
    gsh[row] = INF_BITS;
    gv[row]  = INF_BITS;
  }
}

// ---------------- Phase 1: bf16 MFMA GEMM + fused semihard-min epilogue ----------
// R6 structure + R9 delta: register-footprint cut to unlock occupancy.
//  - R8 diagnosis: combined VGPR(64)+AGPR(64)=128/wave -> 16 waves/CU cap
//    (unified gfx950 file, pool 512/SIMD); LDS/threads never bound.
//  - R9: 512-thread blocks, 8 waves (2M x 4N), per-wave 64x32 -> acc 32 regs,
//    est. combined ~78. __launch_bounds__(512,6): cap 512/6=85 >= need (~78),
//    giving 6 waves/SIMD = 3 blocks/CU = 24 waves (75%).
// Same 128x128 tile, BK=64, global_load_lds, T2 both-sides XOR swizzle
// (conflicts=0), 2D-chunked XCD swizzle (FETCH 37MB), aliased epilogue LDS.
__global__ __launch_bounds__(512, 6) void gemm_min_kernel(
    const unsigned short* __restrict__ a_bf, const unsigned short* __restrict__ n_bf,
    const float* __restrict__ a2, const float* __restrict__ n2,
    const float* __restrict__ dap, const int* __restrict__ ta, const int* __restrict__ tn,
    unsigned* __restrict__ gsh, unsigned* __restrict__ gv, int D, int nj) {
  __shared__ unsigned short ldsA[128 * 64];   // [row][64 bf16] = 128B/row, 16KB
  __shared__ unsigned short ldsB[128 * 64];   // total 32KB

  const int tid  = threadIdx.x;
  const int lane = tid & 63;
  const int wid  = tid >> 6;          // 0..7
  const int wm   = wid >> 2;          // 0..1 (M half: rows wm*64..+63)
  const int wn   = wid & 3;           // 0..3 (N quarter: cols wn*32..+31)
  const int lg   = lane >> 4;         // 0..3 (K-group within frag)
  const int lc   = lane & 15;         // 0..15 (row within frag)

  // ---- 2D-chunked XCD swizzle (R6-proven) ----
  const int bid = (int)blockIdx.x;
  int it, jt;
  if ((nj & 7) == 0) {
    const int band = nj >> 3;            // i-tiles per XCD (8 for N=8192)
    const int xcd  = bid & 7;
    const int l    = bid >> 3;           // local index within XCD [0, nj*band)
    const int q    = l / (band * 8);     // j super-square index [0, nj/8)
    const int s    = l - q * (band * 8); // [0, band*8)
    it = xcd * band + (s >> 3);
    jt = q * 8 + (s & 7);
  } else {                               // fallback: 1D bijective swizzle
    const int wg = (bid & 7) * ((int)gridDim.x >> 3) + (bid >> 3);
    it = wg / nj; jt = wg % nj;
  }
  const int i0 = it * 128;
  const int j0 = jt * 128;

  // staging geometry (512 thr): one gload instr = 512x16B = 8KB = 64 rows x 128B.
  // lane-linear LDS dest (tid*16B), swizzled global source col (rule #21).
  const int srow = tid >> 3;                       // 0..63
  const int scol = (((tid & 7) ^ (srow & 7)) << 3);// swizzled source col (elems)

  // hoisted per-part base offsets (elem offsets; fit 32-bit)
  unsigned baseA[2], baseB[2];
  #pragma unroll
  for (int p = 0; p < 2; p++) {
    baseA[p] = (unsigned)((i0 + p * 64 + srow) * D + scol);
    baseB[p] = (unsigned)((j0 + p * 64 + srow) * D + scol);
  }

  f32x4 acc[4][2];
  #pragma unroll
  for (int m = 0; m < 4; m++)
    #pragma unroll
    for (int n = 0; n < 2; n++)
      acc[m][n] = (f32x4){0.f, 0.f, 0.f, 0.f};

  const int ps0 = lg ^ (lc & 7);   // physical slot for kk=0; kk=1 is ps0^4
  const int nt  = D >> 6;          // 8 K-tiles

  for (int t = 0; t < nt; ++t) {
    const int kc = t << 6;
    __syncthreads();   // previous K-step's reads done before overwrite
    #pragma unroll
    for (int p = 0; p < 2; p++) {
      __builtin_amdgcn_global_load_lds(
          (const __attribute__((address_space(1))) void*)(a_bf + baseA[p] + kc),
          (__attribute__((address_space(3))) void*)(ldsA + p * 4096 + (tid << 3)),
          16, 0, 0);
      __builtin_amdgcn_global_load_lds(
          (const __attribute__((address_space(1))) void*)(n_bf + baseB[p] + kc),
          (__attribute__((address_space(3))) void*)(ldsB + p * 4096 + (tid << 3)),
          16, 0, 0);
    }
    __syncthreads();   // compiler drains vmcnt before barrier -> LDS ready

    #pragma unroll
    for (int kk = 0; kk < 2; kk++) {
      const int ps = (kk == 0) ? ps0 : (ps0 ^ 4);
      bfrag aF[4], bF[2];
      #pragma unroll
      for (int m = 0; m < 4; m++)
        aF[m] = *(const bfrag*)(ldsA + (wm*64 + m*16 + lc) * 64 + (ps << 3));
      #pragma unroll
      for (int n = 0; n < 2; n++)
        bF[n] = *(const bfrag*)(ldsB + (wn*32 + n*16 + lc) * 64 + (ps << 3));
      __builtin_amdgcn_s_setprio(1);
      #pragma unroll
      for (int m = 0; m < 4; m++)
        #pragma unroll
        for (int n = 0; n < 2; n++)
          acc[m][n] = __builtin_amdgcn_mfma_f32_16x16x32_bf16(aF[m], bF[n], acc[m][n], 0, 0, 0);
      __builtin_amdgcn_s_setprio(0);
    }
  }

  // ---- fused epilogue: min arrays aliased into ldsA (tiles dead now) ----
  __syncthreads();   // all waves done reading tiles
  unsigned* lds_mv  = (unsigned*)ldsA;         // [128]
  unsigned* lds_msh = ((unsigned*)ldsA) + 128; // [128]
  if (tid < 128) { lds_mv[tid] = INF_BITS; lds_msh[tid] = INF_BITS; }
  __syncthreads();

  float n2c[2], thrc[2];
  int tnc[2];
  #pragma unroll
  for (int n = 0; n < 2; n++) {
    const int j = j0 + wn * 32 + n * 16 + lc;
    n2c[n]  = n2[j];
    tnc[n]  = tn[j];
    thrc[n] = dap[j] + MARGIN;   // column-indexed d_ap[j], replicating reference
  }
  #pragma unroll
  for (int m = 0; m < 4; m++) {
    #pragma unroll
    for (int r = 0; r < 4; r++) {
      const int il = wm*64 + m*16 + lg*4 + r;   // C row = (lane>>4)*4 + reg (m89-verified)
      const int i  = i0 + il;
      const float a2i = a2[i];
      const int   tai = ta[i];
      float mv = __uint_as_float(INF_BITS);
      float ms = mv;
      #pragma unroll
      for (int n = 0; n < 2; n++) {
        float d = a2i + n2c[n] - 2.0f * acc[m][n][r];
        bool valid = (tai != tnc[n]);
        if (valid) {
          mv = fminf(mv, d);
          if (d > thrc[n]) ms = fminf(ms, d);
        }
      }
      #pragma unroll
      for (int off = 1; off <= 8; off <<= 1) {  // min over 16-lane column group
        mv = fminf(mv, __shfl_xor(mv, off));
        ms = fminf(ms, __shfl_xor(ms, off));
      }
      if (lc == 0) {   // positive floats: uint order == float order
        atomicMin(&lds_mv[il],  __float_as_uint(mv));
        atomicMin(&lds_msh[il], __float_as_uint(ms));
      }
    }
  }

  __syncthreads();
  if (tid < 128) {
    atomicMin(&gv[i0 + tid],  lds_mv[tid]);
    atomicMin(&gsh[i0 + tid], lds_msh[tid]);
  }
}

// ---------------- Phase 2: d_an select + mean(relu) ----------------
__global__ __launch_bounds__(256) void finalize_kernel(
    const float* __restrict__ dap, const unsigned* __restrict__ gsh,
    const unsigned* __restrict__ gv, float* __restrict__ out, int n) {
  __shared__ float red[4];
  float s = 0.f;
  for (int i = threadIdx.x; i < n; i += 256) {
    const unsigned u = gsh[i];
    const unsigned b = (u == INF_BITS) ? gv[i] : u;   // fall back to hardest
    const float dan = __uint_as_float(b);
    const float t = dap[i] - dan + MARGIN;
    s += fmaxf(t, 0.f);
  }
  #pragma unroll
  for (int off = 32; off > 0; off >>= 1) s += __shfl_down(s, off);
  if ((threadIdx.x & 63) == 0) red[threadIdx.x >> 6] = s;
  __syncthreads();
  if (threadIdx.x == 0) out[0] = (red[0] + red[1] + red[2] + red[3]) / (float)n;
}

extern "C" void kernel_launch(void* const* d_in, const int* in_sizes, int n_in,
                              void* d_out, int out_size, void* d_ws, size_t ws_size,
                              hipStream_t stream) {
  const float* anchor   = (const float*)d_in[0];
  const float* positive = (const float*)d_in[1];
  const float* negative = (const float*)d_in[2];
  const int*   ta       = (const int*)d_in[3];
  const int*   tn       = (const int*)d_in[4];
  const int N = in_sizes[3];
  const int D = in_sizes[0] / N;

  // workspace layout
  unsigned short* a_bf = (unsigned short*)d_ws;                 // N*D bf16
  unsigned short* n_bf = a_bf + (size_t)N * D;                  // N*D bf16
  float* a2  = (float*)(n_bf + (size_t)N * D);                  // N f32
  float* n2  = a2 + N;
  float* dap = n2 + N;
  unsigned* gsh = (unsigned*)(dap + N);                         // N u32 (min bits)
  unsigned* gv  = gsh + N;
  const size_t needed = (size_t)N * D * 4 + (size_t)N * 20;
  if (ws_size < needed) return;  // deterministic failure signature if ws too small

  const int nj  = N / 128;
  const int nwg = nj * nj;   // 4096 for N=8192; % 8 == 0

  prep_kernel<<<N / 4, 256, 0, stream>>>(anchor, positive, negative,
                                         a_bf, n_bf, a2, n2, dap, gsh, gv, D);
  gemm_min_kernel<<<nwg, 512, 0, stream>>>(a_bf, n_bf, a2, n2, dap,
                                           ta, tn, gsh, gv, D, nj);
  finalize_kernel<<<1, 256, 0, stream>>>(dap, gsh, gv, (float*)d_out, N);
}

// Round 10
// 110.951 us; speedup vs baseline: 1.3012x; 1.3012x over previous
//
#include <hip/hip_runtime.h>
#include <stdint.h>

#define MARGIN 0.2f
#define INF_BITS 0x7F800000u

typedef __attribute__((ext_vector_type(8))) short bfrag;     // 8 bf16 (4 VGPRs)
typedef __attribute__((ext_vector_type(4))) float f32x4;

__device__ __forceinline__ unsigned short f32_to_bf16(float f) {
  unsigned u = __float_as_uint(f);
  u += 0x7FFFu + ((u >> 16) & 1u);   // RNE
  return (unsigned short)(u >> 16);
}

// ---------------- Phase 0: norms, d_ap, bf16 conversion, min-init ----------------
// one wave per row (4 rows/block)
__global__ __launch_bounds__(256) void prep_kernel(
    const float* __restrict__ anchor, const float* __restrict__ positive,
    const float* __restrict__ negative,
    unsigned short* __restrict__ a_bf, unsigned short* __restrict__ n_bf,
    float* __restrict__ a2, float* __restrict__ n2, float* __restrict__ dap,
    unsigned* __restrict__ gsh, unsigned* __restrict__ gv, int D) {
  const int wid  = threadIdx.x >> 6;
  const int lane = threadIdx.x & 63;
  const int row  = blockIdx.x * 4 + wid;
  const size_t base = (size_t)row * D;
  const int epl = D >> 6;            // elements per lane (8 for D=512)
  const int k0  = lane * epl;
  float sa2 = 0.f, sdap = 0.f, sn2 = 0.f;

  for (int c = 0; c < epl; c += 8) {
    const float4* ap = (const float4*)(anchor   + base + k0 + c);
    const float4* pp = (const float4*)(positive + base + k0 + c);
    const float4* np = (const float4*)(negative + base + k0 + c);
    float4 a0 = ap[0], a1 = ap[1];
    float4 p0 = pp[0], p1 = pp[1];
    float4 v0 = np[0], v1 = np[1];
    float aa[8] = {a0.x,a0.y,a0.z,a0.w,a1.x,a1.y,a1.z,a1.w};
    float pv[8] = {p0.x,p0.y,p0.z,p0.w,p1.x,p1.y,p1.z,p1.w};
    float nn[8] = {v0.x,v0.y,v0.z,v0.w,v1.x,v1.y,v1.z,v1.w};
    #pragma unroll
    for (int e = 0; e < 8; e++) {
      sa2 += aa[e] * aa[e];
      float dd = aa[e] - pv[e];
      sdap += dd * dd;
      sn2 += nn[e] * nn[e];
    }
    unsigned au[4], nu[4];
    #pragma unroll
    for (int e = 0; e < 4; e++) {
      au[e] = (unsigned)f32_to_bf16(aa[2*e]) | ((unsigned)f32_to_bf16(aa[2*e+1]) << 16);
      nu[e] = (unsigned)f32_to_bf16(nn[2*e]) | ((unsigned)f32_to_bf16(nn[2*e+1]) << 16);
    }
    *(uint4*)(a_bf + base + k0 + c) = make_uint4(au[0], au[1], au[2], au[3]);
    *(uint4*)(n_bf + base + k0 + c) = make_uint4(nu[0], nu[1], nu[2], nu[3]);
  }
  #pragma unroll
  for (int off = 32; off > 0; off >>= 1) {
    sa2  += __shfl_down(sa2,  off);
    sdap += __shfl_down(sdap, off);
    sn2  += __shfl_down(sn2,  off);
  }
  if (lane == 0) {
    a2[row]  = sa2;
    dap[row] = sdap;
    n2[row]  = sn2;
    gsh[row] = INF_BITS;
    gv[row]  = INF_BITS;
  }
}

// ---------------- Phase 1: bf16 MFMA GEMM + fused semihard-min epilogue ----------
// R6 configuration verbatim — best measured across 9 variants (104.8 µs, 655 TF):
// 128x128 tile, BK=64, 4 waves (2x2), 4 blocks/CU, global_load_lds staging,
// T2 both-sides XOR swizzle (conflicts=0), 2D-chunked XCD swizzle (FETCH 37MB).
// Deep-pipeline ports (R3/R4/R5), occupancy pushes (R7/R8/R9) all regressed.
__global__ __launch_bounds__(256, 4) void gemm_min_kernel(
    const unsigned short* __restrict__ a_bf, const unsigned short* __restrict__ n_bf,
    const float* __restrict__ a2, const float* __restrict__ n2,
    const float* __restrict__ dap, const int* __restrict__ ta, const int* __restrict__ tn,
    unsigned* __restrict__ gsh, unsigned* __restrict__ gv, int D, int nj) {
  __shared__ unsigned short ldsA[128 * 64];   // [row][64 bf16] = 128B/row, 16KB
  __shared__ unsigned short ldsB[128 * 64];
  __shared__ unsigned lds_msh[128];
  __shared__ unsigned lds_mv[128];

  const int tid  = threadIdx.x;
  const int lane = tid & 63;
  const int wid  = tid >> 6;
  const int wr   = wid >> 1, wc = wid & 1;   // 2x2 wave grid, 64x64 per wave
  const int lg   = lane >> 4;                // 0..3 (K-group within frag)
  const int lc   = lane & 15;                // 0..15 (row within frag)

  // ---- 2D-chunked XCD swizzle (R6-proven) ----
  const int bid = (int)blockIdx.x;
  int it, jt;
  if ((nj & 7) == 0) {
    const int band = nj >> 3;            // i-tiles per XCD (8 for N=8192)
    const int xcd  = bid & 7;
    const int l    = bid >> 3;           // local index within XCD [0, nj*band)
    const int q    = l / (band * 8);     // j super-square index [0, nj/8)
    const int s    = l - q * (band * 8); // [0, band*8)
    it = xcd * band + (s >> 3);
    jt = q * 8 + (s & 7);
  } else {                               // fallback: 1D bijective swizzle
    const int wg = (bid & 7) * ((int)gridDim.x >> 3) + (bid >> 3);
    it = wg / nj; jt = wg % nj;
  }
  const int i0 = it * 128;
  const int j0 = jt * 128;

  if (tid < 128) { lds_msh[tid] = INF_BITS; lds_mv[tid] = INF_BITS; }

  // staging geometry: 1KB LDS chunk = 8 rows x 128B; lane l -> row q*8+(l>>3),
  // physical slot (l&7); source column = (slot_phys ^ row&7)*8 elements
  const int srow8 = lane >> 3;                     // 0..7 == row&7 for this lane
  const int scol  = ((lane & 7) ^ srow8) << 3;     // swizzled source col (elems)

  f32x4 acc[4][4];
  #pragma unroll
  for (int m = 0; m < 4; m++)
    #pragma unroll
    for (int n = 0; n < 4; n++)
      acc[m][n] = (f32x4){0.f, 0.f, 0.f, 0.f};

  const int ps0 = lg ^ (lc & 7);   // physical slot for kk=0; kk=1 is ps0^4

  for (int k0 = 0; k0 < D; k0 += 64) {
    __syncthreads();   // previous K-step's reads done before overwrite
    #pragma unroll
    for (int c = 0; c < 4; c++) {
      const int q   = (wid << 2) + c;       // 1KB chunk id, wave-uniform
      const int row = (q << 3) + srow8;
      const unsigned short* ga = a_bf + (size_t)(i0 + row) * D + k0 + scol;
      const unsigned short* gb = n_bf + (size_t)(j0 + row) * D + k0 + scol;
      __builtin_amdgcn_global_load_lds(
          (const __attribute__((address_space(1))) void*)ga,
          (__attribute__((address_space(3))) void*)(ldsA + q * 512), 16, 0, 0);
      __builtin_amdgcn_global_load_lds(
          (const __attribute__((address_space(1))) void*)gb,
          (__attribute__((address_space(3))) void*)(ldsB + q * 512), 16, 0, 0);
    }
    __syncthreads();   // compiler drains vmcnt before barrier -> LDS ready

    #pragma unroll
    for (int kk = 0; kk < 2; kk++) {
      const int ps = (kk == 0) ? ps0 : (ps0 ^ 4);
      bfrag aF[4], bF[4];
      #pragma unroll
      for (int m = 0; m < 4; m++)
        aF[m] = *(const bfrag*)(ldsA + (wr*64 + m*16 + lc) * 64 + (ps << 3));
      #pragma unroll
      for (int n = 0; n < 4; n++)
        bF[n] = *(const bfrag*)(ldsB + (wc*64 + n*16 + lc) * 64 + (ps << 3));
      #pragma unroll
      for (int m = 0; m < 4; m++)
        #pragma unroll
        for (int n = 0; n < 4; n++)
          acc[m][n] = __builtin_amdgcn_mfma_f32_16x16x32_bf16(aF[m], bF[n], acc[m][n], 0, 0, 0);
    }
  }

  // ---- fused epilogue: d = a2[i] + n2[j] - 2*dot; masks; row-min ----
  float n2c[4], thrc[4];
  int tnc[4];
  const int jb = j0 + wc * 64;
  #pragma unroll
  for (int n = 0; n < 4; n++) {
    const int j = jb + n * 16 + lc;
    n2c[n]  = n2[j];
    tnc[n]  = tn[j];
    thrc[n] = dap[j] + MARGIN;   // column-indexed d_ap[j], replicating reference
  }
  #pragma unroll
  for (int m = 0; m < 4; m++) {
    #pragma unroll
    for (int r = 0; r < 4; r++) {
      const int il = wr*64 + m*16 + lg*4 + r;   // C row = (lane>>4)*4 + reg (m89-verified)
      const int i  = i0 + il;
      const float a2i = a2[i];
      const int   tai = ta[i];
      float mv = __uint_as_float(INF_BITS);
      float ms = mv;
      #pragma unroll
      for (int n = 0; n < 4; n++) {
        float d = a2i + n2c[n] - 2.0f * acc[m][n][r];
        bool valid = (tai != tnc[n]);
        if (valid) {
          mv = fminf(mv, d);
          if (d > thrc[n]) ms = fminf(ms, d);
        }
      }
      #pragma unroll
      for (int off = 1; off <= 8; off <<= 1) {  // min over 16-lane column group
        mv = fminf(mv, __shfl_xor(mv, off));
        ms = fminf(ms, __shfl_xor(ms, off));
      }
      if (lc == 0) {   // positive floats: uint order == float order
        atomicMin(&lds_mv[il],  __float_as_uint(mv));
        atomicMin(&lds_msh[il], __float_as_uint(ms));
      }
    }
  }

  __syncthreads();
  if (tid < 128) {
    atomicMin(&gv[i0 + tid],  lds_mv[tid]);
    atomicMin(&gsh[i0 + tid], lds_msh[tid]);
  }
}

// ---------------- Phase 2: d_an select + mean(relu), vectorized ----------------
__global__ __launch_bounds__(256) void finalize_kernel(
    const float* __restrict__ dap, const unsigned* __restrict__ gsh,
    const unsigned* __restrict__ gv, float* __restrict__ out, int n) {
  __shared__ float red[4];
  float s = 0.f;
  const uint4*  g4 = (const uint4*)gsh;
  const uint4*  v4 = (const uint4*)gv;
  const float4* d4 = (const float4*)dap;
  const int nv = n >> 2;                      // 2048 vec4 groups
  for (int i = threadIdx.x; i < nv; i += 256) {
    const uint4  us = g4[i];
    const uint4  uv = v4[i];
    const float4 dd = d4[i];
    const unsigned su[4] = {us.x, us.y, us.z, us.w};
    const unsigned vu[4] = {uv.x, uv.y, uv.z, uv.w};
    const float    df[4] = {dd.x, dd.y, dd.z, dd.w};
    #pragma unroll
    for (int e = 0; e < 4; e++) {
      const unsigned b = (su[e] == INF_BITS) ? vu[e] : su[e];   // semihard else hardest
      const float dan = __uint_as_float(b);
      s += fmaxf(df[e] - dan + MARGIN, 0.f);
    }
  }
  #pragma unroll
  for (int off = 32; off > 0; off >>= 1) s += __shfl_down(s, off);
  if ((threadIdx.x & 63) == 0) red[threadIdx.x >> 6] = s;
  __syncthreads();
  if (threadIdx.x == 0) out[0] = (red[0] + red[1] + red[2] + red[3]) / (float)n;
}

extern "C" void kernel_launch(void* const* d_in, const int* in_sizes, int n_in,
                              void* d_out, int out_size, void* d_ws, size_t ws_size,
                              hipStream_t stream) {
  const float* anchor   = (const float*)d_in[0];
  const float* positive = (const float*)d_in[1];
  const float* negative = (const float*)d_in[2];
  const int*   ta       = (const int*)d_in[3];
  const int*   tn       = (const int*)d_in[4];
  const int N = in_sizes[3];
  const int D = in_sizes[0] / N;

  // workspace layout
  unsigned short* a_bf = (unsigned short*)d_ws;                 // N*D bf16
  unsigned short* n_bf = a_bf + (size_t)N * D;                  // N*D bf16
  float* a2  = (float*)(n_bf + (size_t)N * D);                  // N f32
  float* n2  = a2 + N;
  float* dap = n2 + N;
  unsigned* gsh = (unsigned*)(dap + N);                         // N u32 (min bits)
  unsigned* gv  = gsh + N;
  const size_t needed = (size_t)N * D * 4 + (size_t)N * 20;
  if (ws_size < needed) return;  // deterministic failure signature if ws too small

  const int nj  = N / 128;
  const int nwg = nj * nj;   // 4096 for N=8192; % 8 == 0

  prep_kernel<<<N / 4, 256, 0, stream>>>(anchor, positive, negative,
                                         a_bf, n_bf, a2, n2, dap, gsh, gv, D);
  gemm_min_kernel<<<nwg, 256, 0, stream>>>(a_bf, n_bf, a2, n2, dap,
                                           ta, tn, gsh, gv, D, nj);
  finalize_kernel<<<1, 256, 0, stream>>>(dap, gsh, gv, (float*)d_out, N);
}